// Round 11
// baseline (490.246 us; speedup 1.0000x reference)
//
#include <hip/hip_runtime.h>

typedef __attribute__((ext_vector_type(8))) short short8;
typedef __attribute__((ext_vector_type(4))) float float4_t;
typedef __attribute__((ext_vector_type(16))) float f32x16;
typedef __attribute__((ext_vector_type(4))) unsigned short ushort4_t;

#define NR 8192
#define C 128
#define SPLITK 4
#define KCHUNK (NR / SPLITK)   // 2048
#define BK 64
#define STEPS (KCHUNK / BK)    // 32

// Static device scratch (fully rewritten each call; no reliance on ws_size).
__device__ unsigned short g_Lb[(size_t)NR * NR];    // packed bf16 L: [mb][kq][r][8] (128 MB)
__device__ unsigned short g_xbT[(size_t)C * NR];    // xbT[c][n] = bf16(x[n][c])
__device__ unsigned short g_T1b[(size_t)NR * C];    // row-major bf16 T1
__device__ unsigned short g_T1bT[(size_t)C * NR];   // T1bT[c][n] = bf16(T1[n][c])
__device__ unsigned short g_Wb[3 * C * C];          // bf16 W
__device__ float g_part[(size_t)SPLITK * NR * C];   // split-K partials (16 MB)

__device__ __forceinline__ unsigned short f2bf(float f) {
  union { float f; unsigned u; } v; v.f = f;
  unsigned r = v.u + 0x7fffu + ((v.u >> 16) & 1u);  // RNE
  return (unsigned short)(r >> 16);
}
__device__ __forceinline__ unsigned pk2(float a, float b) {
  union { float f; unsigned u; } x, y; x.f = a; y.f = b;
  unsigned ra = x.u + 0x7fffu + ((x.u >> 16) & 1u);
  unsigned rb = y.u + 0x7fffu + ((y.u >> 16) & 1u);
  return (ra >> 16) | (rb & 0xffff0000u);
}
__device__ __forceinline__ short8 cvt8(float4_t f0, float4_t f1) {
  union { unsigned u[4]; short8 s; } r;
  r.u[0] = pk2(f0[0], f0[1]); r.u[1] = pk2(f0[2], f0[3]);
  r.u[2] = pk2(f1[0], f1[1]); r.u[3] = pk2(f1[2], f1[3]);
  return r.s;
}

typedef __attribute__((address_space(3))) unsigned lds_uint;
typedef const __attribute__((address_space(1))) unsigned glob_uint;
__device__ __forceinline__ void gload_lds16(const void* g, void* l) {
  __builtin_amdgcn_global_load_lds((glob_uint*)g, (lds_uint*)l, 16, 0, 0);
}

// ---- tiny: W fp32 -> bf16 ---------------------------------------------------
__global__ void cvt_w(const float* __restrict__ W) {
  int i = (blockIdx.x * 256 + threadIdx.x) * 4;
  float4_t v = *(const float4_t*)(W + i);
  ushort4_t h; h[0]=f2bf(v[0]); h[1]=f2bf(v[1]); h[2]=f2bf(v[2]); h[3]=f2bf(v[3]);
  *(ushort4_t*)(g_Wb + i) = h;
}

// ---- pack L: fp32 row-major -> bf16 [mb][kq][r][8] --------------------------
// Reads full-width row segments (2 KB/row-visit, page-friendly); writes one
// contiguous 64 KB run per block. At HBM roofline (~61 us for 384 MB).
__global__ __launch_bounds__(256) void pack_l(const float* __restrict__ L) {
  __shared__ __attribute__((aligned(16))) unsigned short tile[64][520];
  int mb = blockIdx.x;   // 0..127
  int y  = blockIdx.y;   // 0..15
  int t = threadIdx.x;
#pragma unroll
  for (int it = 0; it < 32; it++) {
    int idx = it * 256 + t;        // f4 index 0..8191
    int row = idx >> 7;            // local row 0..63
    int c4  = idx & 127;           // f4 within row
    float4_t v = *(const float4_t*)(L + (size_t)(mb * 64 + row) * NR + y * 512 + c4 * 4);
    ushort4_t h; h[0]=f2bf(v[0]); h[1]=f2bf(v[1]); h[2]=f2bf(v[2]); h[3]=f2bf(v[3]);
    *(ushort4_t*)(&tile[row][c4 * 4]) = h;
  }
  __syncthreads();
  // unit u = kql*64 + r  (kql = local kq 0..63, r = local row 0..63)
  unsigned short* dst = g_Lb + (size_t)(mb * 1024 + y * 64) * 512;  // *64 rows *8 elems
#pragma unroll
  for (int j = 0; j < 16; j++) {
    int u = j * 256 + t;
    int kql = u >> 6, r = u & 63;
    short8 h = *(const short8*)(&tile[r][kql * 8]);   // contiguous 16B in LDS row
    *(short8*)(dst + (size_t)u * 8) = h;              // per-wave contiguous 1KB
  }
}

// ---- x [8192][128] fp32 -> xbT [128][8192] bf16 -----------------------------
__global__ void transpose_x(const float* __restrict__ x) {
  __shared__ unsigned short xt[64][72];
  int r0 = blockIdx.x * 64;
  int c0 = blockIdx.y * 64;
  int t = threadIdx.x;
  int rr = t >> 4;
  int cc = (t & 15) * 4;
#pragma unroll
  for (int i = 0; i < 4; i++) {
    int row = i * 16 + rr;
    float4_t v = *(const float4_t*)(x + (size_t)(r0 + row) * C + c0 + cc);
    ushort4_t h; h[0]=f2bf(v[0]); h[1]=f2bf(v[1]); h[2]=f2bf(v[2]); h[3]=f2bf(v[3]);
    *(ushort4_t*)(&xt[row][cc]) = h;
  }
  __syncthreads();
  int c = t >> 2, q = t & 3;   // c 0..63, q: 16-row group
  unsigned short* dst = g_xbT + (size_t)(c0 + c) * NR + r0 + q * 16;
#pragma unroll
  for (int seg = 0; seg < 2; seg++) {
    short8 h;
#pragma unroll
    for (int j = 0; j < 8; j++) h[j] = (short)xt[q * 16 + seg * 8 + j][c];
    *(short8*)(dst + seg * 8) = h;   // 16B stores
  }
}

// ---- GEMM: part = Lb(bf16 packed) @ B ; BM=64, BN=128, BK=64 ----------------
// 32x32x16 MFMA: same operand bytes per instruction as 16x16x32 but 2x the
// FLOPs -> halves LDS read traffic. Per wave per step: 4 A-reads + 8 B-reads
// + 8 MFMA (was 2+16+16). Per-CU step cost drops ~2100 -> ~1535 cyc, below
// the 1600-cyc HBM budget: kernel becomes HBM-bound (was LDS-read-bound,
// which is why triple-buffer depth only bought 5 us).
// Wave (mw,nw): m-half mw*32, n-half nw*64 (two 32-wide n-tiles).
// TRIPLE-buffered LDS, depth-2 prefetch, vmcnt(12) steady state.
// which==0: BT=g_xbT (T1); which==1: BT=g_T1bT (U).
__global__ __launch_bounds__(256, 2) void gemm_cheb(int which) {
  const unsigned short* __restrict__ BT = which ? g_T1bT : g_xbT;
  __shared__ __attribute__((aligned(16))) unsigned short As[3][64 * BK];   // 3x8 KB
  __shared__ __attribute__((aligned(16))) unsigned short Bs[3][128 * BK];  // 3x16 KB
  int tid = threadIdx.x;
  int wave = tid >> 6, lane = tid & 63;
  int l31 = lane & 31, hi = lane >> 5;
  int mw = wave & 1, nw = wave >> 1;
  int m0 = blockIdx.x * 64;
  int kb = blockIdx.y * KCHUNK;

  // A staging: 8 KB/step = 512 units of 16B; unit = kq_local*64 + r.
  const unsigned short* pA[2];
  size_t abase = (size_t)(blockIdx.x * 1024 + blockIdx.y * (KCHUNK / 8)) * 512;
#pragma unroll
  for (int i = 0; i < 2; i++)
    pA[i] = g_Lb + abase + (size_t)((wave * 2 + i) * 64 + lane) * 8;

  // B staging: 128 n x 64 bf16 = 16KB = 8 units of 16B per row (XOR-swizzled).
  const unsigned short* pB[4];
#pragma unroll
  for (int i = 0; i < 4; i++) {
    int U = (wave * 4 + i) * 64 + lane;   // 0..1023
    int n = U >> 3, p = U & 7;
    pB[i] = BT + (size_t)n * NR + kb + ((p ^ (n & 7)) << 3);
  }

  f32x16 acc0, acc1;
#pragma unroll
  for (int i = 0; i < 16; i++) { acc0[i] = 0.f; acc1[i] = 0.f; }

  #define ISSUE(buf)                                                         \
    do {                                                                     \
      _Pragma("unroll")                                                      \
      for (int i = 0; i < 2; i++)                                            \
        gload_lds16(pA[i], (char*)&As[buf][0] + (wave * 2 + i) * 1024);      \
      _Pragma("unroll")                                                      \
      for (int i = 0; i < 4; i++)                                            \
        gload_lds16(pB[i], (char*)&Bs[buf][0] + (wave * 4 + i) * 1024);      \
      _Pragma("unroll")                                                      \
      for (int i = 0; i < 2; i++) pA[i] += 8 * 64 * 8;                       \
      _Pragma("unroll")                                                      \
      for (int i = 0; i < 4; i++) pB[i] += BK;                               \
    } while (0)

  // 32x32x16 fragments from the existing layouts:
  //  A: lane holds row=mw*32+l31, k-octet kq=2s+hi of slice s -> unit kq*64+row.
  //  B: lane holds n=tile*32+l31, k-octet 2s+hi -> Bs byte n*128 + (kq^(n&7))*16.
  // Both reads hit the 8-cyc wave64-b128 structural floor (checked).
  #define COMPUTE(buf)                                                       \
    do {                                                                     \
      _Pragma("unroll")                                                      \
      for (int s = 0; s < 4; s++) {                                          \
        int kq = 2 * s + hi;                                                 \
        short8 a = *(const short8*)((const char*)&As[buf][0] +               \
                                    ((kq * 64 + mw * 32 + l31) << 4));       \
        int n0 = nw * 64 + l31;                                              \
        int pb = kq ^ (n0 & 7);                                              \
        short8 b0 = *(const short8*)((const char*)&Bs[buf][0] + n0 * 128 + pb * 16);           \
        acc0 = __builtin_amdgcn_mfma_f32_32x32x16_bf16(a, b0, acc0, 0, 0, 0);                  \
        short8 b1 = *(const short8*)((const char*)&Bs[buf][0] + (n0 + 32) * 128 + pb * 16);    \
        acc1 = __builtin_amdgcn_mfma_f32_32x32x16_bf16(a, b1, acc1, 0, 0, 0);                  \
      }                                                                      \
    } while (0)

  ISSUE(0);
  ISSUE(1);
  int p = 0;
  for (int step = 0; step < STEPS - 2; step++) {
    int nxt = p + 2; if (nxt >= 3) nxt -= 3;
    ISSUE(nxt);                                          // prefetch step+2
    // outstanding: 6 (step) + 6 (step+1) + 6 (step+2); wait step's only.
    asm volatile("s_waitcnt vmcnt(12)" ::: "memory");
    asm volatile("s_barrier" ::: "memory");              // everyone's are done
    COMPUTE(p);
    asm volatile("s_barrier" ::: "memory");              // buf p free to overwrite
    p = p + 1; if (p >= 3) p -= 3;
  }
  // step STEPS-2: outstanding 12; wait its 6.
  asm volatile("s_waitcnt vmcnt(6)" ::: "memory");
  asm volatile("s_barrier" ::: "memory");
  COMPUTE(p);
  p = p + 1; if (p >= 3) p -= 3;
  // step STEPS-1
  asm volatile("s_waitcnt vmcnt(0)" ::: "memory");
  asm volatile("s_barrier" ::: "memory");
  COMPUTE(p);

  // C/D 32x32 layout: col = l31, row = (reg&3) + 8*(reg>>2) + 4*hi.
  float* po = g_part + (size_t)blockIdx.y * NR * C;
  int mbase = m0 + mw * 32 + hi * 4;
  int nbase = nw * 64 + l31;
#pragma unroll
  for (int reg = 0; reg < 16; reg++) {
    int rl = (reg & 3) + 8 * (reg >> 2);
    po[(size_t)(mbase + rl) * C + nbase] = acc0[reg];
    po[(size_t)(mbase + rl) * C + nbase + 32] = acc1[reg];
  }
  #undef ISSUE
  #undef COMPUTE
}

// ---- reduce split-K partials -> T1 bf16 (row-major + transposed) ------------
__global__ void reduce_t1() {
  __shared__ unsigned short tile[16][136];
  int r0 = blockIdx.x * 16;
  int t = threadIdx.x;
#pragma unroll
  for (int e = 0; e < 2; e++) {
    int linear = e * 1024 + t * 4;
    int r = linear >> 7, c = linear & 127;
    float4_t s = (float4_t){0.f, 0.f, 0.f, 0.f};
#pragma unroll
    for (int p = 0; p < SPLITK; p++)
      s += *(const float4_t*)(g_part + (size_t)p * NR * C + (size_t)(r0 + r) * C + c);
    ushort4_t h; h[0]=f2bf(s[0]); h[1]=f2bf(s[1]); h[2]=f2bf(s[2]); h[3]=f2bf(s[3]);
    *(ushort4_t*)(g_T1b + (size_t)(r0 + r) * C + c) = h;
    *(ushort4_t*)(&tile[r][c]) = h;
  }
  __syncthreads();
  int c = t >> 1, half = t & 1;
  short8 h;
#pragma unroll
  for (int j = 0; j < 8; j++) h[j] = (short)tile[half * 8 + j][c];
  *(short8*)(g_T1bT + (size_t)c * NR + r0 + half * 8) = h;   // 16B store
}

// ---- epilogue: reduce U partials, T2 = 2U - x, out = sum_j T_j W_j^T --------
__global__ __launch_bounds__(256) void epilogue(const float* __restrict__ x,
                                                float* __restrict__ out) {
  __shared__ unsigned short t2[32][136];
  int r0 = blockIdx.x * 32;
  int t = threadIdx.x;
#pragma unroll
  for (int e = 0; e < 4; e++) {
    int linear = e * 1024 + t * 4;
    int r = linear >> 7, c = linear & 127;
    float4_t s = (float4_t){0.f, 0.f, 0.f, 0.f};
#pragma unroll
    for (int p = 0; p < SPLITK; p++)
      s += *(const float4_t*)(g_part + (size_t)p * NR * C + (size_t)(r0 + r) * C + c);
    float4_t xv = *(const float4_t*)(x + (size_t)(r0 + r) * C + c);
    float4_t t2v = 2.0f * s - xv;
    ushort4_t h; h[0]=f2bf(t2v[0]); h[1]=f2bf(t2v[1]); h[2]=f2bf(t2v[2]); h[3]=f2bf(t2v[3]);
    *(ushort4_t*)(&t2[r][c]) = h;
  }
  __syncthreads();

  int wave = t >> 6, lane = t & 63, l15 = lane & 15, lq = lane >> 4;
  int mf = wave & 1, nh = wave >> 1;
  int m0r = r0 + mf * 16;
  float4_t acc[4];
#pragma unroll
  for (int ni = 0; ni < 4; ni++) acc[ni] = (float4_t){0.f, 0.f, 0.f, 0.f};

#pragma unroll
  for (int ks = 0; ks < 4; ks++) {
    int k0 = ks * 32 + lq * 8;
    const float* px = x + (size_t)(m0r + l15) * C + k0;
    float4_t f0 = *(const float4_t*)px;
    float4_t f1 = *(const float4_t*)(px + 4);
    short8 a0 = cvt8(f0, f1);
    short8 a1 = *(const short8*)(g_T1b + (size_t)(m0r + l15) * C + k0);
    short8 a2 = *(const short8*)(&t2[mf * 16 + l15][k0]);
#pragma unroll
    for (int ni = 0; ni < 4; ni++) {
      int n = nh * 64 + ni * 16 + l15;
      const unsigned short* pw = g_Wb + (size_t)n * C + k0;
      short8 w0 = *(const short8*)(pw);
      short8 w1 = *(const short8*)(pw + C * C);
      short8 w2 = *(const short8*)(pw + 2 * C * C);
      acc[ni] = __builtin_amdgcn_mfma_f32_16x16x32_bf16(a0, w0, acc[ni], 0, 0, 0);
      acc[ni] = __builtin_amdgcn_mfma_f32_16x16x32_bf16(a1, w1, acc[ni], 0, 0, 0);
      acc[ni] = __builtin_amdgcn_mfma_f32_16x16x32_bf16(a2, w2, acc[ni], 0, 0, 0);
    }
  }
#pragma unroll
  for (int ni = 0; ni < 4; ni++)
#pragma unroll
    for (int r = 0; r < 4; r++)
      out[(size_t)(m0r + lq * 4 + r) * C + nh * 64 + ni * 16 + l15] = acc[ni][r];
}

extern "C" void kernel_launch(void* const* d_in, const int* in_sizes, int n_in,
                              void* d_out, int out_size, void* d_ws, size_t ws_size,
                              hipStream_t stream) {
  const float* x = (const float*)d_in[0];   // [8192][128]
  const float* L = (const float*)d_in[1];   // [8192][8192]
  const float* W = (const float*)d_in[2];   // [3][128][128]
  float* out = (float*)d_out;               // [8192][128]

  cvt_w<<<48, 256, 0, stream>>>(W);
  transpose_x<<<dim3(128, 2), 256, 0, stream>>>(x);
  pack_l<<<dim3(128, 16), 256, 0, stream>>>(L);            // L -> bf16 packed
  gemm_cheb<<<dim3(128, SPLITK), 256, 0, stream>>>(0);     // T1 partials
  reduce_t1<<<512, 256, 0, stream>>>();                    // -> T1b, T1bT
  gemm_cheb<<<dim3(128, SPLITK), 256, 0, stream>>>(1);     // U partials
  epilogue<<<256, 256, 0, stream>>>(x, out);               // T2 + three W-GEMMs
}